// Round 13
// baseline (923.219 us; speedup 1.0000x reference)
//
#include <hip/hip_runtime.h>
#include <hip/hip_bf16.h>

#define NN 100000
#define EE 300000
#define GG 4000
#define LL 5
#define GPB 4
#define SC_CHUNK 1024
#define SC_NB ((NN + SC_CHUNK - 1) / SC_CHUNK)   // 98

typedef _Float16 half8  __attribute__((ext_vector_type(8)));
typedef _Float16 half4v __attribute__((ext_vector_type(4)));
typedef float    f32x4  __attribute__((ext_vector_type(4)));

__device__ inline short f2h(float f) {
    _Float16 h = (_Float16)f;
    short s; __builtin_memcpy(&s, &h, 2); return s;
}

__device__ inline void async_load16(const void* g, void* l) {
    __builtin_amdgcn_global_load_lds(
        (const __attribute__((address_space(1))) unsigned int*)g,
        (__attribute__((address_space(3))) unsigned int*)l, 16, 0, 0);
}

// ---------------- CSR build ----------------
__global__ __launch_bounds__(256) void k_count(
    int* __restrict__ deg, const int* __restrict__ ei)
{
    int e = blockIdx.x * 256 + threadIdx.x;
    if (e < EE) atomicAdd(&deg[ei[EE + e]], 1);
}

__global__ __launch_bounds__(256) void k_scan_partial(
    int* __restrict__ partial, const int* __restrict__ deg)
{
    int b = blockIdx.x, t = threadIdx.x;
    int lane = t & 63, w = t >> 6;
    int base = b * SC_CHUNK + t * 4;
    int s = 0;
#pragma unroll
    for (int j = 0; j < 4; ++j) {
        int i = base + j;
        if (i < NN) s += deg[i];
    }
#pragma unroll
    for (int off = 1; off < 64; off <<= 1) s += __shfl_xor(s, off, 64);
    __shared__ int ws[4];
    if (lane == 0) ws[w] = s;
    __syncthreads();
    if (t == 0) partial[b] = ws[0] + ws[1] + ws[2] + ws[3];
}

__global__ __launch_bounds__(128) void k_scan_base(
    int* __restrict__ bases, int* __restrict__ offs, const int* __restrict__ partial)
{
    int t = threadIdx.x;
    int lane = t & 63, w = t >> 6;
    int p = (t < SC_NB) ? partial[t] : 0;
    int x = p;
#pragma unroll
    for (int off = 1; off < 64; off <<= 1) {
        int nb = __shfl_up(x, off, 64);
        if (lane >= off) x += nb;
    }
    __shared__ int w0tot;
    if (t == 63) w0tot = x;
    __syncthreads();
    if (w == 1) x += w0tot;
    if (t < SC_NB) bases[t] = x - p;
    if (t == 0) offs[NN] = EE;
}

__global__ __launch_bounds__(256) void k_scan_final(
    int* __restrict__ offs, int* __restrict__ cursor,
    const int* __restrict__ deg, const int* __restrict__ bases)
{
    int b = blockIdx.x, t = threadIdx.x;
    int lane = t & 63, w = t >> 6;
    int base = b * SC_CHUNK + t * 4;
    int v[4], pre[4], run = 0;
#pragma unroll
    for (int j = 0; j < 4; ++j) {
        int i = base + j;
        v[j] = (i < NN) ? deg[i] : 0;
        pre[j] = run;
        run += v[j];
    }
    int x = run;
#pragma unroll
    for (int off = 1; off < 64; off <<= 1) {
        int nb = __shfl_up(x, off, 64);
        if (lane >= off) x += nb;
    }
    int tex = x - run;
    __shared__ int ws[4];
    if (lane == 63) ws[w] = x;
    __syncthreads();
    int woff = 0;
    for (int k = 0; k < 4; ++k) if (k < w) woff += ws[k];
    int tbase = bases[b] + woff + tex;
#pragma unroll
    for (int j = 0; j < 4; ++j) {
        int i = base + j;
        if (i < NN) { offs[i] = tbase + pre[j]; cursor[i] = tbase + pre[j]; }
    }
}

__global__ __launch_bounds__(256) void k_fill(
    int* __restrict__ csr, int* __restrict__ cursor,
    const int* __restrict__ ei, const int* __restrict__ ea)
{
    int e = blockIdx.x * 256 + threadIdx.x;
    if (e >= EE) return;
    int s = ei[e];
    int d = ei[EE + e];
    int c = ea[2 * e] * 3 + ea[2 * e + 1];
    int slot = atomicAdd(&cursor[d], 1);
    csr[slot] = s | (c << 20);
}

// ---------------- weight pack body (shared by fused prologue) ------------
__device__ __forceinline__ void pack_body(
    short* __restrict__ dst, const float* __restrict__ src, int K, int Nsz,
    int nb, int kb, int l, int t, float (*T)[65])
{
    const float* s = src + ((size_t)l * K + kb * 32) * Nsz + nb * 64;
#pragma unroll
    for (int i = 0; i < 8; ++i) {
        int idx = i * 256 + t;
        int kk = idx >> 6, nl = idx & 63;
        T[kk][nl] = s[(size_t)kk * Nsz + nl];
    }
    __syncthreads();
    int nl = t >> 2, kq = t & 3;
    union { short s[8]; int4 v; } o;
#pragma unroll
    for (int j = 0; j < 8; ++j) o.s[j] = f2h(T[kq * 8 + j][nl]);
    short* d = dst + (((size_t)l * (K / 32) + kb) * Nsz + nb * 64 + nl) * 32 + kq * 8;
    *(int4*)d = o.v;
}

// ---------------- fused prologue: all independent setup in ONE dispatch --
// R20 (kept): role-split by blockIdx. [0,391) goffs; [391,441) combo;
// [441,761) pack W1; [761,1081) pack W2; [1081,1145) pack_emb;
// [1145,1536) deg=0; [1536,1568) stats=0. Replaces 5 kernels + 2 memsets.
__global__ __launch_bounds__(256) void k_prologue(
    int* __restrict__ goffs, const int* __restrict__ batch,
    float* __restrict__ tbl, const float* __restrict__ ee1, const float* __restrict__ ee2,
    short* __restrict__ W1p, const float* __restrict__ W1,
    short* __restrict__ W2p, const float* __restrict__ W2,
    _Float16* __restrict__ Wep, const float* __restrict__ embW,
    int* __restrict__ deg, float* __restrict__ stats)
{
    __shared__ float T[32][65];
    int b = blockIdx.x, t = threadIdx.x;
    if (b < 391) {
        int n = b * 256 + t;
        if (n >= NN) return;
        int bb = batch[n];
        int bp = (n == 0) ? -1 : batch[n - 1];
        for (int g = bp + 1; g <= bb; ++g) goffs[g] = n;
        if (n == NN - 1)
            for (int g = bb + 1; g <= GG; ++g) goffs[g] = NN;
    } else if (b < 441) {
        int idx = b - 391;
        int c = idx % 10, l = idx / 10;
        int i1 = (c < 9) ? c / 3 : 4;
        int i2 = (c < 9) ? c % 3 : 0;
        tbl[((size_t)l * 10 + c) * 256 + t] =
            ee1[((size_t)l * 6 + i1) * 256 + t] + ee2[((size_t)l * 3 + i2) * 256 + t];
    } else if (b < 761) {
        int idx = b - 441;
        pack_body(W1p, W1, 256, 512, idx & 7, (idx >> 3) & 7, idx >> 6, t, T);
    } else if (b < 1081) {
        int idx = b - 761;
        pack_body(W2p, W2, 512, 256, idx & 3, (idx >> 2) & 15, idx >> 6, t, T);
    } else if (b < 1145) {
        int idx = (b - 1081) * 256 + t;
        int ks = idx >> 13, r = idx & 8191;
        int n = r >> 5, kk = r & 31;
        int k = ks * 32 + kk;
        float v = (k < 40) ? embW[(size_t)k * 256 + n] : 0.f;
        Wep[idx] = (_Float16)v;
    } else if (b < 1536) {
        int n = (b - 1145) * 256 + t;
        if (n < NN) deg[n] = 0;
    } else {
        int gi = (b - 1536) * 1024 + t * 4;
        float4 z = {0.f, 0.f, 0.f, 0.f};
        *(float4*)(stats + gi) = z;
    }
}

// ---------------- embed via MFMA ----------------
__global__ __launch_bounds__(256) void k_embed_mfma(
    _Float16* __restrict__ H, const float* __restrict__ x,
    const _Float16* __restrict__ Wep, const float* __restrict__ bias)
{
    __shared__ __align__(16) char smem[67584];
    _Float16* As = (_Float16*)smem;
    _Float16* Bs = (_Float16*)(smem + 16384);
    _Float16* Cs = (_Float16*)smem;

    const int t = threadIdx.x;
    const int w = t >> 6, lane = t & 63;
    const int quad = lane >> 4, l16 = lane & 15;
    const int wr = w >> 1, wc = w & 1;
    const int gm0 = blockIdx.x * 128;

#pragma unroll
    for (int i = 0; i < 8; ++i) {
        int u = i * 256 + t;
        async_load16((const char*)Wep + u * 16, (char*)Bs + u * 16);
    }

    {
        int row = t >> 1, half = t & 1;
        int rg = gm0 + row; if (rg > NN - 1) rg = NN - 1;
        const float* xp = x + (size_t)rg * 40 + half * 20;
        float v[20];
#pragma unroll
        for (int j = 0; j < 5; ++j) {
            float4 q = *(const float4*)(xp + j * 4);
            v[j * 4 + 0] = q.x; v[j * 4 + 1] = q.y; v[j * 4 + 2] = q.z; v[j * 4 + 3] = q.w;
        }
#pragma unroll
        for (int j = 0; j < 20; ++j) {
            int col = half * 20 + j;
            int ks = col >> 5, kk = col & 31;
            As[ks * 4096 + row * 32 + kk] = (_Float16)v[j];
        }
        int kb = 8 + half * 12;
#pragma unroll
        for (int j = 0; j < 12; ++j)
            As[4096 + row * 32 + kb + j] = (_Float16)0.f;
    }

    float biasreg[8];
#pragma unroll
    for (int nt = 0; nt < 8; ++nt)
        biasreg[nt] = bias[wc * 128 + nt * 16 + l16];

    f32x4 acc[4][8];
#pragma unroll
    for (int i = 0; i < 4; ++i)
#pragma unroll
        for (int j = 0; j < 8; ++j) acc[i][j] = (f32x4){0.f, 0.f, 0.f, 0.f};

    __syncthreads();

#pragma unroll
    for (int ks = 0; ks < 2; ++ks) {
        half8 af[4], bfr[8];
#pragma unroll
        for (int mt = 0; mt < 4; ++mt)
            af[mt] = *(const half8*)(As + ks * 4096 + (wr * 64 + mt * 16 + l16) * 32 + quad * 8);
#pragma unroll
        for (int nt = 0; nt < 8; ++nt)
            bfr[nt] = *(const half8*)(Bs + ks * 8192 + (wc * 128 + nt * 16 + l16) * 32 + quad * 8);
#pragma unroll
        for (int mt = 0; mt < 4; ++mt)
#pragma unroll
            for (int nt = 0; nt < 8; ++nt)
                acc[mt][nt] = __builtin_amdgcn_mfma_f32_16x16x32_f16(
                    af[mt], bfr[nt], acc[mt][nt], 0, 0, 0);
    }

    __syncthreads();
#pragma unroll
    for (int mt = 0; mt < 4; ++mt)
#pragma unroll
        for (int nt = 0; nt < 8; ++nt)
#pragma unroll
            for (int r = 0; r < 4; ++r) {
                int row = wr * 64 + mt * 16 + quad * 4 + r;
                int col = wc * 128 + nt * 16 + l16;
                Cs[row * 264 + col] = (_Float16)fmaxf(acc[mt][nt][r] + biasreg[nt], 0.f);
            }
    __syncthreads();
#pragma unroll
    for (int i = 0; i < 16; ++i) {
        int u = i * 256 + t;
        int m = u >> 5, ch = u & 31;
        int grow = gm0 + m;
        if (grow < NN)
            *(int4*)(H + (size_t)grow * 256 + ch * 8) =
                *(const int4*)(Cs + m * 264 + ch * 8);
    }
}

// ---------------- fused aggregate (R19: 2 rows/wave, half8 loads) --------
template <int AFF>
__global__ __launch_bounds__(256) void k_aggregate(
    _Float16* __restrict__ agg, const _Float16* __restrict__ hin,
    const int* __restrict__ offs, const int* __restrict__ csr,
    const float* __restrict__ tbl,
    const float* __restrict__ scale, const float* __restrict__ shift)
{
    int t = threadIdx.x;
    int w = t >> 6, lane = t & 63;
    int half = lane >> 5, l32 = lane & 31;
    int n = blockIdx.x * 8 + w * 2 + half;
    int ci = l32 * 2;                 // f32x4 index of this lane's 8 channels

    const f32x4* tb4 = (const f32x4*)tbl;

    f32x4 sc0, sc1, sh0, sh1;
    if (AFF) {
        sc0 = ((const f32x4*)scale)[ci];  sc1 = ((const f32x4*)scale)[ci + 1];
        sh0 = ((const f32x4*)shift)[ci];  sh1 = ((const f32x4*)shift)[ci + 1];
    }

    half8 hv = *(const half8*)(hin + (size_t)n * 256 + l32 * 8);
    f32x4 a0 = tb4[9 * 64 + ci];
    f32x4 a1 = tb4[9 * 64 + ci + 1];
#pragma unroll
    for (int q = 0; q < 4; ++q) {
        float v0 = (float)hv[q];
        float v1 = (float)hv[4 + q];
        if (AFF) { v0 = fmaf(v0, sc0[q], sh0[q]); v1 = fmaf(v1, sc1[q], sh1[q]); }
        a0[q] += fmaxf(v0, 0.f);
        a1[q] += fmaxf(v1, 0.f);
    }

    int o0 = offs[n], o1 = offs[n + 1];
    for (int e = o0; e < o1; ++e) {
        int entry = csr[e];
        int s = entry & 0xFFFFF;
        int c = entry >> 20;
        half8 gv = *(const half8*)(hin + (size_t)s * 256 + l32 * 8);
        f32x4 t0 = tb4[c * 64 + ci];
        f32x4 t1 = tb4[c * 64 + ci + 1];
#pragma unroll
        for (int q = 0; q < 4; ++q) {
            float v0 = (float)gv[q];
            float v1 = (float)gv[4 + q];
            if (AFF) { v0 = fmaf(v0, sc0[q], sh0[q]); v1 = fmaf(v1, sc1[q], sh1[q]); }
            a0[q] += fmaxf(v0, 0.f) + t0[q];
            a1[q] += fmaxf(v1, 0.f) + t1[q];
        }
    }

    half8 o;
#pragma unroll
    for (int q = 0; q < 4; ++q) {
        o[q]     = (_Float16)a0[q];
        o[4 + q] = (_Float16)a1[q];
    }
    *(half8*)(agg + (size_t)n * 256 + l32 * 8) = o;
}

// ---------------- fused MLP: h2 = (relu(agg@W1+b1))@W2 + b2, + BN stats ---
// R24 = R10 mlp (100-102us, best measured, stable across 3 containers).
// R25: + T5 s_setprio(1) around the MFMA clusters. Mechanism: 3 blocks/CU
// run phase-shifted; raising compute-phase wave priority wins issue slots
// from staging-phase blocks (m191-style independent-block diversity).
// Null-result read (pre-committed): mlp unchanged => structure plateau.
__global__ __launch_bounds__(256, 3) void k_fused_mlp(
    _Float16* __restrict__ H2, const _Float16* __restrict__ A,
    const short* __restrict__ W1p, const float* __restrict__ b1,
    const short* __restrict__ W2p, const float* __restrict__ b2,
    float* __restrict__ stats)
{
    __shared__ __align__(16) char smem[40960];
    _Float16* As = (_Float16*)smem;              // [64][256] granule-XOR, 32 KB
    _Float16* Us = (_Float16*)(smem + 32768);    // [64][64] granule-XOR, 8 KB
    _Float16* Cs = (_Float16*)smem;              // epilogue [64][264] (overlay)

    const int t = threadIdx.x;
    const int w = t >> 6, lane = t & 63;
    const int quad = lane >> 4, l16 = lane & 15;
    const int bm = blockIdx.x;
    const int gm0 = bm * 64;
    const int swz = l16 & 7;

    // stage A tile (64x256 f16 = 32 KB), granule g of row r at slot g^(r&7)
#pragma unroll
    for (int i = 0; i < 8; ++i) {
        int u = i * 256 + t;            // 2048 granules
        int row = u >> 5;
        int gcol = (u & 31) ^ (row & 7);
        int grow = gm0 + row; if (grow > NN - 1) grow = NN - 1;
        async_load16(A + (size_t)grow * 256 + gcol * 8, (char*)As + u * 16);
    }

    // per-wave weight base pointers (frag = base + elem-offset)
    const _Float16* w1w = (const _Float16*)W1p + ((size_t)(w * 16 + l16)) * 32 + quad * 8;
    const _Float16* w2w = (const _Float16*)W2p + ((size_t)(w * 64 + l16)) * 32 + quad * 8;

    // deep prefetch: chunk 0's full W1 (8 frags) + kk=0 W2 (4 frags)
    half8 w1buf[8];
#pragma unroll
    for (int i = 0; i < 8; ++i)
        w1buf[i] = *(const half8*)(w1w + ((size_t)i * 512) * 32);
    half8 w2k0[4];
#pragma unroll
    for (int nt = 0; nt < 4; ++nt)
        w2k0[nt] = *(const half8*)(w2w + ((size_t)nt * 16) * 32);

    f32x4 acc2[4][4];
#pragma unroll
    for (int i = 0; i < 4; ++i)
#pragma unroll
        for (int j = 0; j < 4; ++j) acc2[i][j] = (f32x4){0.f, 0.f, 0.f, 0.f};

    __syncthreads();   // staging barrier: must drain vmcnt (global_load_lds)

    for (int j = 0; j < 8; ++j) {
        // ---- GEMM1 chunk: U^T (64 uc x 64 ur) — pure LDS+MFMA, no VMEM --
        f32x4 acc1[4];
#pragma unroll
        for (int b = 0; b < 4; ++b) acc1[b] = (f32x4){0.f, 0.f, 0.f, 0.f};

        __builtin_amdgcn_s_setprio(1);
#pragma unroll
        for (int kb = 0; kb < 8; ++kb) {
            int slotA = (kb * 4 + quad) ^ swz;
            half8 b1f[4];
#pragma unroll
            for (int urt = 0; urt < 4; ++urt)
                b1f[urt] = *(const half8*)(As + (urt * 16 + l16) * 256 + slotA * 8);
#pragma unroll
            for (int urt = 0; urt < 4; ++urt)
                acc1[urt] = __builtin_amdgcn_mfma_f32_16x16x32_f16(
                    w1buf[kb], b1f[urt], acc1[urt], 0, 0, 0);
        }
        __builtin_amdgcn_s_setprio(0);

        // issue kk=1 W2 frags NOW -> latency hides under Us-write + barrier
        half8 a2n[4];
#pragma unroll
        for (int nt = 0; nt < 4; ++nt)
            a2n[nt] = *(const half8*)(w2w + ((size_t)(j * 2 + 1) * 256 + nt * 16) * 32);

        // write U chunk: relu(v+b1) -> f16, granule G of row ur at G^(ur&7)
        {
            int ucl = w * 16 + quad * 4;
            float4 bv = *(const float4*)(b1 + j * 64 + ucl);
            int G = ucl >> 3;
            int hs = quad & 1;
#pragma unroll
            for (int urt = 0; urt < 4; ++urt) {
                int ur = urt * 16 + l16;
                int S = G ^ (ur & 7);
                half4v o;
                o[0] = (_Float16)fmaxf(acc1[urt][0] + bv.x, 0.f);
                o[1] = (_Float16)fmaxf(acc1[urt][1] + bv.y, 0.f);
                o[2] = (_Float16)fmaxf(acc1[urt][2] + bv.z, 0.f);
                o[3] = (_Float16)fmaxf(acc1[urt][3] + bv.w, 0.f);
                *(half4v*)(Us + ur * 64 + S * 8 + hs * 4) = o;
            }
        }
        // LDS-only hazard: Us writes -> Us reads. Do NOT drain vmcnt here.
        asm volatile("s_waitcnt lgkmcnt(0)" ::: "memory");
        __builtin_amdgcn_s_barrier();
        __builtin_amdgcn_sched_barrier(0);

        // ---- GEMM2: refill next chunk's W1 (needed next GEMM1) ----
        if (j < 7) {
#pragma unroll
            for (int i = 0; i < 8; ++i)
                w1buf[i] = *(const half8*)(w1w + ((size_t)i * 512 + (j + 1) * 64) * 32);
        }

        // kk = 0 (weights in w2k0, prefetched one full chunk ago)
        __builtin_amdgcn_s_setprio(1);
        {
            int slotU = quad ^ swz;
            half8 b2f[4];
#pragma unroll
            for (int mt = 0; mt < 4; ++mt)
                b2f[mt] = *(const half8*)(Us + (mt * 16 + l16) * 64 + slotU * 8);
#pragma unroll
            for (int nt = 0; nt < 4; ++nt)
#pragma unroll
                for (int mt = 0; mt < 4; ++mt)
                    acc2[nt][mt] = __builtin_amdgcn_mfma_f32_16x16x32_f16(
                        w2k0[nt], b2f[mt], acc2[nt][mt], 0, 0, 0);
        }
        __builtin_amdgcn_s_setprio(0);
        // refill w2k0 for next chunk's kk=0
        if (j < 7) {
#pragma unroll
            for (int nt = 0; nt < 4; ++nt)
                w2k0[nt] = *(const half8*)(w2w + ((size_t)(j + 1) * 2 * 256 + nt * 16) * 32);
        }
        // kk = 1 (weights in a2n)
        __builtin_amdgcn_s_setprio(1);
        {
            int slotU = (4 + quad) ^ swz;
            half8 b2f[4];
#pragma unroll
            for (int mt = 0; mt < 4; ++mt)
                b2f[mt] = *(const half8*)(Us + (mt * 16 + l16) * 64 + slotU * 8);
#pragma unroll
            for (int nt = 0; nt < 4; ++nt)
#pragma unroll
                for (int mt = 0; mt < 4; ++mt)
                    acc2[nt][mt] = __builtin_amdgcn_mfma_f32_16x16x32_f16(
                        a2n[nt], b2f[mt], acc2[nt][mt], 0, 0, 0);
        }
        __builtin_amdgcn_s_setprio(0);
        // LDS-only hazard: Us reads -> next chunk's Us writes.
        asm volatile("s_waitcnt lgkmcnt(0)" ::: "memory");
        __builtin_amdgcn_s_barrier();
        __builtin_amdgcn_sched_barrier(0);
    }

    // ---- epilogue: bias + BN stats, coalesced store via LDS overlay ----
    int slot2 = bm & 63;
#pragma unroll
    for (int nt = 0; nt < 4; ++nt) {
        int nb = w * 64 + nt * 16 + quad * 4;
        float4 bv = *(const float4*)(b2 + nb);
        float s1[4] = {0.f, 0.f, 0.f, 0.f};
        float s2[4] = {0.f, 0.f, 0.f, 0.f};
#pragma unroll
        for (int mt = 0; mt < 4; ++mt) {
            int mr = mt * 16 + l16;
            int m = gm0 + mr;
            float v0 = acc2[nt][mt][0] + bv.x;
            float v1 = acc2[nt][mt][1] + bv.y;
            float v2 = acc2[nt][mt][2] + bv.z;
            float v3 = acc2[nt][mt][3] + bv.w;
            half4v o;
            o[0] = (_Float16)v0; o[1] = (_Float16)v1;
            o[2] = (_Float16)v2; o[3] = (_Float16)v3;
            *(half4v*)(Cs + mr * 264 + nb) = o;
            if (m < NN) {
                s1[0] += v0; s1[1] += v1; s1[2] += v2; s1[3] += v3;
                s2[0] += v0 * v0; s2[1] += v1 * v1;
                s2[2] += v2 * v2; s2[3] += v3 * v3;
            }
        }
#pragma unroll
        for (int r = 0; r < 4; ++r) {
            s1[r] += __shfl_xor(s1[r], 1, 64); s2[r] += __shfl_xor(s2[r], 1, 64);
            s1[r] += __shfl_xor(s1[r], 2, 64); s2[r] += __shfl_xor(s2[r], 2, 64);
            s1[r] += __shfl_xor(s1[r], 4, 64); s2[r] += __shfl_xor(s2[r], 4, 64);
            s1[r] += __shfl_xor(s1[r], 8, 64); s2[r] += __shfl_xor(s2[r], 8, 64);
            if (l16 == 0) {
                atomicAdd(&stats[slot2 * 512 + nb + r], s1[r]);
                atomicAdd(&stats[slot2 * 512 + 256 + nb + r], s2[r]);
            }
        }
    }
    __syncthreads();
#pragma unroll
    for (int i = 0; i < 8; ++i) {
        int u = i * 256 + t;
        int m = u >> 5, ch = u & 31;
        int grow = gm0 + m;
        if (grow < NN)
            *(int4*)(H2 + (size_t)grow * 256 + ch * 8) =
                *(const int4*)(Cs + m * 264 + ch * 8);
    }
}

// ---------------- BN finalize (+zero stats for next layer) ----------------
__global__ __launch_bounds__(256) void k_bn_finalize(
    float* __restrict__ scale, float* __restrict__ shift,
    float* __restrict__ stats,
    const float* __restrict__ bn_g, const float* __restrict__ bn_b)
{
    int t = threadIdx.x;
    float s1 = 0.f, s2 = 0.f;
    for (int j = 0; j < 64; ++j) {
        s1 += stats[j * 512 + t];
        s2 += stats[j * 512 + 256 + t];
        stats[j * 512 + t] = 0.f;
        stats[j * 512 + 256 + t] = 0.f;
    }
    float mu  = s1 / (float)NN;
    float var = s2 / (float)NN - mu * mu;
    float sc  = bn_g[t] * rsqrtf(var + 1e-5f);
    scale[t] = sc;
    shift[t] = bn_b[t] - mu * sc;
}

// ---------------- pool (R24: vectorized half8 loads, 8 rows in flight) ---
__global__ __launch_bounds__(256) void k_pool(
    float* __restrict__ mol, const _Float16* __restrict__ h,
    const int* __restrict__ goffs,
    const float* __restrict__ scale, const float* __restrict__ shift)
{
    __shared__ float red[8][256];
    int g = blockIdx.x;
    int t = threadIdx.x;
    int rg = t >> 5, c8 = t & 31;
    int s = goffs[g], e = goffs[g + 1];

    float acc[8] = {0.f,0.f,0.f,0.f,0.f,0.f,0.f,0.f};
    for (int n = s + rg; n < e; n += 8) {
        half8 v = *(const half8*)(h + (size_t)n * 256 + c8 * 8);
#pragma unroll
        for (int q = 0; q < 8; ++q) acc[q] += (float)v[q];
    }
#pragma unroll
    for (int q = 0; q < 8; ++q) red[rg][c8 * 8 + q] = acc[q];
    __syncthreads();

    float sum = 0.f;
#pragma unroll
    for (int r = 0; r < 8; ++r) sum += red[r][t];
    int c = e - s; if (c < 1) c = 1;
    mol[(size_t)g * 256 + t] = fmaf(sum / (float)c, scale[t], shift[t]);
}

// ---------------- head MLP, 4 graphs/block, 1000 blocks ----------------
__global__ __launch_bounds__(256) void k_head(
    float* __restrict__ out, const float* __restrict__ mol,
    const float* __restrict__ hW0, const float* __restrict__ hb0,
    const float* __restrict__ hW1, const float* __restrict__ hb1,
    const float* __restrict__ hW2, const float* __restrict__ hb2,
    const float* __restrict__ hW3, const float* __restrict__ hb3,
    const float* __restrict__ hWo, const float* __restrict__ hbo)
{
    __shared__ float za[GPB][256];
    __shared__ float zb[GPB][256];
    const int t = threadIdx.x;
    const int g0 = blockIdx.x * GPB;

#pragma unroll
    for (int g = 0; g < GPB; ++g)
        za[g][t] = mol[(size_t)(g0 + g) * 256 + t];
    __syncthreads();

    {
        float acc[GPB];
#pragma unroll
        for (int g = 0; g < GPB; ++g) acc[g] = 0.f;
        for (int k = 0; k < 256; ++k) {
            float w = hW0[k * 256 + t];
#pragma unroll
            for (int g = 0; g < GPB; ++g) acc[g] = fmaf(za[g][k], w, acc[g]);
        }
        float b = hb0[t];
#pragma unroll
        for (int g = 0; g < GPB; ++g) zb[g][t] = fmaxf(acc[g] + b, 0.f);
    }
    __syncthreads();

    if (t < 128) {
        float acc[GPB];
#pragma unroll
        for (int g = 0; g < GPB; ++g) acc[g] = 0.f;
        for (int k = 0; k < 256; ++k) {
            float w = hW1[k * 128 + t];
#pragma unroll
            for (int g = 0; g < GPB; ++g) acc[g] = fmaf(zb[g][k], w, acc[g]);
        }
        float b = hb1[t];
#pragma unroll
        for (int g = 0; g < GPB; ++g) za[g][t] = fmaxf(acc[g] + b, 0.f);
    }
    __syncthreads();

    if (t < 64) {
        float acc[GPB];
#pragma unroll
        for (int g = 0; g < GPB; ++g) acc[g] = 0.f;
        for (int k = 0; k < 128; ++k) {
            float w = hW2[k * 64 + t];
#pragma unroll
            for (int g = 0; g < GPB; ++g) acc[g] = fmaf(za[g][k], w, acc[g]);
        }
        float b = hb2[t];
#pragma unroll
        for (int g = 0; g < GPB; ++g) zb[g][t] = fmaxf(acc[g] + b, 0.f);
    }
    __syncthreads();

    if (t < 32) {
        float acc[GPB];
#pragma unroll
        for (int g = 0; g < GPB; ++g) acc[g] = 0.f;
        for (int k = 0; k < 64; ++k) {
            float w = hW3[k * 32 + t];
#pragma unroll
            for (int g = 0; g < GPB; ++g) acc[g] = fmaf(zb[g][k], w, acc[g]);
        }
        float b = hb3[t];
#pragma unroll
        for (int g = 0; g < GPB; ++g) za[g][t] = fmaxf(acc[g] + b, 0.f);
    }
    __syncthreads();

    if (t < GPB) {
        float s = hbo[0];
        for (int k = 0; k < 32; ++k) s = fmaf(za[t][k], hWo[k], s);
        out[g0 + t] = s;
    }
}

extern "C" void kernel_launch(void* const* d_in, const int* in_sizes, int n_in,
                              void* d_out, int out_size, void* d_ws, size_t ws_size,
                              hipStream_t stream)
{
    const float* x    = (const float*)d_in[0];
    const int*   ei   = (const int*)d_in[1];
    const int*   ea   = (const int*)d_in[2];
    const int*   batch= (const int*)d_in[3];
    const float* embW = (const float*)d_in[4];
    const float* embB = (const float*)d_in[5];
    const float* ee1  = (const float*)d_in[6];
    const float* ee2  = (const float*)d_in[7];
    const float* W1   = (const float*)d_in[8];
    const float* b1   = (const float*)d_in[9];
    const float* W2   = (const float*)d_in[10];
    const float* b2   = (const float*)d_in[11];
    const float* bng  = (const float*)d_in[12];
    const float* bnb  = (const float*)d_in[13];
    const float* hW0  = (const float*)d_in[14];
    const float* hb0  = (const float*)d_in[15];
    const float* hW1  = (const float*)d_in[16];
    const float* hb1  = (const float*)d_in[17];
    const float* hW2  = (const float*)d_in[18];
    const float* hb2  = (const float*)d_in[19];
    const float* hW3  = (const float*)d_in[20];
    const float* hb3  = (const float*)d_in[21];
    const float* hWo  = (const float*)d_in[22];
    const float* hbo  = (const float*)d_in[23];
    float* out = (float*)d_out;

    char* ws = (char*)d_ws;
    size_t off = 0;
    _Float16* h2buf = (_Float16*)(ws + off); off += (size_t)NN * 256 * 2;
    _Float16* aggbuf= (_Float16*)(ws + off); off += (size_t)NN * 256 * 2;
    short* W1p      = (short*)(ws + off);    off += (size_t)5 * 131072 * 2;
    short* W2p      = (short*)(ws + off);    off += (size_t)5 * 131072 * 2;
    _Float16* Wep   = (_Float16*)(ws + off); off += (size_t)2 * 8192 * 2;
    float* tbl      = (float*)(ws + off);    off += (size_t)5 * 10 * 256 * 4;
    float* stats    = (float*)(ws + off);    off += (size_t)64 * 512 * 4;
    float* scale    = (float*)(ws + off);    off += 256 * 4;
    float* shift    = (float*)(ws + off);    off += 256 * 4;
    float* mol      = (float*)(ws + off);    off += (size_t)GG * 256 * 4;
    int* deg        = (int*)(ws + off);      off += (size_t)NN * 4;
    int* offs       = (int*)(ws + off);      off += (size_t)(NN + 1) * 4;
    int* cursor     = (int*)(ws + off);      off += (size_t)NN * 4;
    int* csr        = (int*)(ws + off);      off += (size_t)EE * 4;
    int* goffs      = (int*)(ws + off);      off += (size_t)(GG + 1) * 4;
    int* partial    = (int*)(ws + off);      off += 128 * 4;
    int* bases      = (int*)(ws + off);      off += 128 * 4;

    // ---- fused prologue (goffs/combo/packs/pack_emb/deg=0/stats=0) ----
    k_prologue<<<1568, 256, 0, stream>>>(goffs, batch, tbl, ee1, ee2,
                                         W1p, W1, W2p, W2, Wep, embW,
                                         deg, stats);
    k_count<<<(EE + 255) / 256, 256, 0, stream>>>(deg, ei);
    k_scan_partial<<<SC_NB, 256, 0, stream>>>(partial, deg);
    k_scan_base<<<1, 128, 0, stream>>>(bases, offs, partial);
    k_scan_final<<<SC_NB, 256, 0, stream>>>(offs, cursor, deg, bases);
    k_fill<<<(EE + 255) / 256, 256, 0, stream>>>(csr, cursor, ei, ea);

    k_embed_mfma<<<782, 256, 0, stream>>>(h2buf, x, Wep, embB);

    const int FB = (NN + 63) / 64;   // 1563
    for (int l = 0; l < LL; ++l) {
        if (l == 0)
            k_aggregate<0><<<NN / 8, 256, 0, stream>>>(aggbuf, h2buf, offs, csr,
                                                       tbl, scale, shift);
        else
            k_aggregate<1><<<NN / 8, 256, 0, stream>>>(aggbuf, h2buf, offs, csr,
                                                       tbl + (size_t)l * 10 * 256, scale, shift);
        k_fused_mlp<<<FB, 256, 0, stream>>>(h2buf, aggbuf,
                                            W1p + (size_t)l * 131072, b1 + l * 512,
                                            W2p + (size_t)l * 131072, b2 + l * 256, stats);
        k_bn_finalize<<<1, 256, 0, stream>>>(scale, shift, stats, bng + l * 256, bnb + l * 256);
    }

    k_pool<<<GG, 256, 0, stream>>>(mol, h2buf, goffs, scale, shift);
    k_head<<<GG / GPB, 256, 0, stream>>>(out, mol,
                                         hW0, hb0, hW1, hb1, hW2, hb2, hW3, hb3, hWo, hbo);
}

// Round 14
// 888.483 us; speedup vs baseline: 1.0391x; 1.0391x over previous
//
#include <hip/hip_runtime.h>
#include <hip/hip_bf16.h>

#define NN 100000
#define EE 300000
#define GG 4000
#define LL 5
#define GPB 4
#define SC_CHUNK 1024
#define SC_NB ((NN + SC_CHUNK - 1) / SC_CHUNK)   // 98

typedef _Float16 half8  __attribute__((ext_vector_type(8)));
typedef _Float16 half4v __attribute__((ext_vector_type(4)));
typedef float    f32x4  __attribute__((ext_vector_type(4)));

__device__ inline short f2h(float f) {
    _Float16 h = (_Float16)f;
    short s; __builtin_memcpy(&s, &h, 2); return s;
}

__device__ inline void async_load16(const void* g, void* l) {
    __builtin_amdgcn_global_load_lds(
        (const __attribute__((address_space(1))) unsigned int*)g,
        (__attribute__((address_space(3))) unsigned int*)l, 16, 0, 0);
}

// ---------------- CSR build ----------------
__global__ __launch_bounds__(256) void k_count(
    int* __restrict__ deg, const int* __restrict__ ei)
{
    int e = blockIdx.x * 256 + threadIdx.x;
    if (e < EE) atomicAdd(&deg[ei[EE + e]], 1);
}

__global__ __launch_bounds__(256) void k_scan_partial(
    int* __restrict__ partial, const int* __restrict__ deg)
{
    int b = blockIdx.x, t = threadIdx.x;
    int lane = t & 63, w = t >> 6;
    int base = b * SC_CHUNK + t * 4;
    int s = 0;
#pragma unroll
    for (int j = 0; j < 4; ++j) {
        int i = base + j;
        if (i < NN) s += deg[i];
    }
#pragma unroll
    for (int off = 1; off < 64; off <<= 1) s += __shfl_xor(s, off, 64);
    __shared__ int ws[4];
    if (lane == 0) ws[w] = s;
    __syncthreads();
    if (t == 0) partial[b] = ws[0] + ws[1] + ws[2] + ws[3];
}

__global__ __launch_bounds__(128) void k_scan_base(
    int* __restrict__ bases, int* __restrict__ offs, const int* __restrict__ partial)
{
    int t = threadIdx.x;
    int lane = t & 63, w = t >> 6;
    int p = (t < SC_NB) ? partial[t] : 0;
    int x = p;
#pragma unroll
    for (int off = 1; off < 64; off <<= 1) {
        int nb = __shfl_up(x, off, 64);
        if (lane >= off) x += nb;
    }
    __shared__ int w0tot;
    if (t == 63) w0tot = x;
    __syncthreads();
    if (w == 1) x += w0tot;
    if (t < SC_NB) bases[t] = x - p;
    if (t == 0) offs[NN] = EE;
}

__global__ __launch_bounds__(256) void k_scan_final(
    int* __restrict__ offs, int* __restrict__ cursor,
    const int* __restrict__ deg, const int* __restrict__ bases)
{
    int b = blockIdx.x, t = threadIdx.x;
    int lane = t & 63, w = t >> 6;
    int base = b * SC_CHUNK + t * 4;
    int v[4], pre[4], run = 0;
#pragma unroll
    for (int j = 0; j < 4; ++j) {
        int i = base + j;
        v[j] = (i < NN) ? deg[i] : 0;
        pre[j] = run;
        run += v[j];
    }
    int x = run;
#pragma unroll
    for (int off = 1; off < 64; off <<= 1) {
        int nb = __shfl_up(x, off, 64);
        if (lane >= off) x += nb;
    }
    int tex = x - run;
    __shared__ int ws[4];
    if (lane == 63) ws[w] = x;
    __syncthreads();
    int woff = 0;
    for (int k = 0; k < 4; ++k) if (k < w) woff += ws[k];
    int tbase = bases[b] + woff + tex;
#pragma unroll
    for (int j = 0; j < 4; ++j) {
        int i = base + j;
        if (i < NN) { offs[i] = tbase + pre[j]; cursor[i] = tbase + pre[j]; }
    }
}

__global__ __launch_bounds__(256) void k_fill(
    int* __restrict__ csr, int* __restrict__ cursor,
    const int* __restrict__ ei, const int* __restrict__ ea)
{
    int e = blockIdx.x * 256 + threadIdx.x;
    if (e >= EE) return;
    int s = ei[e];
    int d = ei[EE + e];
    int c = ea[2 * e] * 3 + ea[2 * e + 1];
    int slot = atomicAdd(&cursor[d], 1);
    csr[slot] = s | (c << 20);
}

// ---------------- weight pack body (shared by fused prologue) ------------
__device__ __forceinline__ void pack_body(
    short* __restrict__ dst, const float* __restrict__ src, int K, int Nsz,
    int nb, int kb, int l, int t, float (*T)[65])
{
    const float* s = src + ((size_t)l * K + kb * 32) * Nsz + nb * 64;
#pragma unroll
    for (int i = 0; i < 8; ++i) {
        int idx = i * 256 + t;
        int kk = idx >> 6, nl = idx & 63;
        T[kk][nl] = s[(size_t)kk * Nsz + nl];
    }
    __syncthreads();
    int nl = t >> 2, kq = t & 3;
    union { short s[8]; int4 v; } o;
#pragma unroll
    for (int j = 0; j < 8; ++j) o.s[j] = f2h(T[kq * 8 + j][nl]);
    short* d = dst + (((size_t)l * (K / 32) + kb) * Nsz + nb * 64 + nl) * 32 + kq * 8;
    *(int4*)d = o.v;
}

// ---------------- fused prologue: all independent setup in ONE dispatch --
// R20 (kept): role-split by blockIdx. [0,391) goffs; [391,441) combo;
// [441,761) pack W1; [761,1081) pack W2; [1081,1145) pack_emb;
// [1145,1536) deg=0; [1536,1568) stats=0. Replaces 5 kernels + 2 memsets.
__global__ __launch_bounds__(256) void k_prologue(
    int* __restrict__ goffs, const int* __restrict__ batch,
    float* __restrict__ tbl, const float* __restrict__ ee1, const float* __restrict__ ee2,
    short* __restrict__ W1p, const float* __restrict__ W1,
    short* __restrict__ W2p, const float* __restrict__ W2,
    _Float16* __restrict__ Wep, const float* __restrict__ embW,
    int* __restrict__ deg, float* __restrict__ stats)
{
    __shared__ float T[32][65];
    int b = blockIdx.x, t = threadIdx.x;
    if (b < 391) {
        int n = b * 256 + t;
        if (n >= NN) return;
        int bb = batch[n];
        int bp = (n == 0) ? -1 : batch[n - 1];
        for (int g = bp + 1; g <= bb; ++g) goffs[g] = n;
        if (n == NN - 1)
            for (int g = bb + 1; g <= GG; ++g) goffs[g] = NN;
    } else if (b < 441) {
        int idx = b - 391;
        int c = idx % 10, l = idx / 10;
        int i1 = (c < 9) ? c / 3 : 4;
        int i2 = (c < 9) ? c % 3 : 0;
        tbl[((size_t)l * 10 + c) * 256 + t] =
            ee1[((size_t)l * 6 + i1) * 256 + t] + ee2[((size_t)l * 3 + i2) * 256 + t];
    } else if (b < 761) {
        int idx = b - 441;
        pack_body(W1p, W1, 256, 512, idx & 7, (idx >> 3) & 7, idx >> 6, t, T);
    } else if (b < 1081) {
        int idx = b - 761;
        pack_body(W2p, W2, 512, 256, idx & 3, (idx >> 2) & 15, idx >> 6, t, T);
    } else if (b < 1145) {
        int idx = (b - 1081) * 256 + t;
        int ks = idx >> 13, r = idx & 8191;
        int n = r >> 5, kk = r & 31;
        int k = ks * 32 + kk;
        float v = (k < 40) ? embW[(size_t)k * 256 + n] : 0.f;
        Wep[idx] = (_Float16)v;
    } else if (b < 1536) {
        int n = (b - 1145) * 256 + t;
        if (n < NN) deg[n] = 0;
    } else {
        int gi = (b - 1536) * 1024 + t * 4;
        float4 z = {0.f, 0.f, 0.f, 0.f};
        *(float4*)(stats + gi) = z;
    }
}

// ---------------- embed via MFMA ----------------
__global__ __launch_bounds__(256) void k_embed_mfma(
    _Float16* __restrict__ H, const float* __restrict__ x,
    const _Float16* __restrict__ Wep, const float* __restrict__ bias)
{
    __shared__ __align__(16) char smem[67584];
    _Float16* As = (_Float16*)smem;
    _Float16* Bs = (_Float16*)(smem + 16384);
    _Float16* Cs = (_Float16*)smem;

    const int t = threadIdx.x;
    const int w = t >> 6, lane = t & 63;
    const int quad = lane >> 4, l16 = lane & 15;
    const int wr = w >> 1, wc = w & 1;
    const int gm0 = blockIdx.x * 128;

#pragma unroll
    for (int i = 0; i < 8; ++i) {
        int u = i * 256 + t;
        async_load16((const char*)Wep + u * 16, (char*)Bs + u * 16);
    }

    {
        int row = t >> 1, half = t & 1;
        int rg = gm0 + row; if (rg > NN - 1) rg = NN - 1;
        const float* xp = x + (size_t)rg * 40 + half * 20;
        float v[20];
#pragma unroll
        for (int j = 0; j < 5; ++j) {
            float4 q = *(const float4*)(xp + j * 4);
            v[j * 4 + 0] = q.x; v[j * 4 + 1] = q.y; v[j * 4 + 2] = q.z; v[j * 4 + 3] = q.w;
        }
#pragma unroll
        for (int j = 0; j < 20; ++j) {
            int col = half * 20 + j;
            int ks = col >> 5, kk = col & 31;
            As[ks * 4096 + row * 32 + kk] = (_Float16)v[j];
        }
        int kb = 8 + half * 12;
#pragma unroll
        for (int j = 0; j < 12; ++j)
            As[4096 + row * 32 + kb + j] = (_Float16)0.f;
    }

    float biasreg[8];
#pragma unroll
    for (int nt = 0; nt < 8; ++nt)
        biasreg[nt] = bias[wc * 128 + nt * 16 + l16];

    f32x4 acc[4][8];
#pragma unroll
    for (int i = 0; i < 4; ++i)
#pragma unroll
        for (int j = 0; j < 8; ++j) acc[i][j] = (f32x4){0.f, 0.f, 0.f, 0.f};

    __syncthreads();

#pragma unroll
    for (int ks = 0; ks < 2; ++ks) {
        half8 af[4], bfr[8];
#pragma unroll
        for (int mt = 0; mt < 4; ++mt)
            af[mt] = *(const half8*)(As + ks * 4096 + (wr * 64 + mt * 16 + l16) * 32 + quad * 8);
#pragma unroll
        for (int nt = 0; nt < 8; ++nt)
            bfr[nt] = *(const half8*)(Bs + ks * 8192 + (wc * 128 + nt * 16 + l16) * 32 + quad * 8);
#pragma unroll
        for (int mt = 0; mt < 4; ++mt)
#pragma unroll
            for (int nt = 0; nt < 8; ++nt)
                acc[mt][nt] = __builtin_amdgcn_mfma_f32_16x16x32_f16(
                    af[mt], bfr[nt], acc[mt][nt], 0, 0, 0);
    }

    __syncthreads();
#pragma unroll
    for (int mt = 0; mt < 4; ++mt)
#pragma unroll
        for (int nt = 0; nt < 8; ++nt)
#pragma unroll
            for (int r = 0; r < 4; ++r) {
                int row = wr * 64 + mt * 16 + quad * 4 + r;
                int col = wc * 128 + nt * 16 + l16;
                Cs[row * 264 + col] = (_Float16)fmaxf(acc[mt][nt][r] + biasreg[nt], 0.f);
            }
    __syncthreads();
#pragma unroll
    for (int i = 0; i < 16; ++i) {
        int u = i * 256 + t;
        int m = u >> 5, ch = u & 31;
        int grow = gm0 + m;
        if (grow < NN)
            *(int4*)(H + (size_t)grow * 256 + ch * 8) =
                *(const int4*)(Cs + m * 264 + ch * 8);
    }
}

// ---------------- fused aggregate (R19: 2 rows/wave, half8 loads) --------
template <int AFF>
__global__ __launch_bounds__(256) void k_aggregate(
    _Float16* __restrict__ agg, const _Float16* __restrict__ hin,
    const int* __restrict__ offs, const int* __restrict__ csr,
    const float* __restrict__ tbl,
    const float* __restrict__ scale, const float* __restrict__ shift)
{
    int t = threadIdx.x;
    int w = t >> 6, lane = t & 63;
    int half = lane >> 5, l32 = lane & 31;
    int n = blockIdx.x * 8 + w * 2 + half;
    int ci = l32 * 2;                 // f32x4 index of this lane's 8 channels

    const f32x4* tb4 = (const f32x4*)tbl;

    f32x4 sc0, sc1, sh0, sh1;
    if (AFF) {
        sc0 = ((const f32x4*)scale)[ci];  sc1 = ((const f32x4*)scale)[ci + 1];
        sh0 = ((const f32x4*)shift)[ci];  sh1 = ((const f32x4*)shift)[ci + 1];
    }

    half8 hv = *(const half8*)(hin + (size_t)n * 256 + l32 * 8);
    f32x4 a0 = tb4[9 * 64 + ci];
    f32x4 a1 = tb4[9 * 64 + ci + 1];
#pragma unroll
    for (int q = 0; q < 4; ++q) {
        float v0 = (float)hv[q];
        float v1 = (float)hv[4 + q];
        if (AFF) { v0 = fmaf(v0, sc0[q], sh0[q]); v1 = fmaf(v1, sc1[q], sh1[q]); }
        a0[q] += fmaxf(v0, 0.f);
        a1[q] += fmaxf(v1, 0.f);
    }

    int o0 = offs[n], o1 = offs[n + 1];
    for (int e = o0; e < o1; ++e) {
        int entry = csr[e];
        int s = entry & 0xFFFFF;
        int c = entry >> 20;
        half8 gv = *(const half8*)(hin + (size_t)s * 256 + l32 * 8);
        f32x4 t0 = tb4[c * 64 + ci];
        f32x4 t1 = tb4[c * 64 + ci + 1];
#pragma unroll
        for (int q = 0; q < 4; ++q) {
            float v0 = (float)gv[q];
            float v1 = (float)gv[4 + q];
            if (AFF) { v0 = fmaf(v0, sc0[q], sh0[q]); v1 = fmaf(v1, sc1[q], sh1[q]); }
            a0[q] += fmaxf(v0, 0.f) + t0[q];
            a1[q] += fmaxf(v1, 0.f) + t1[q];
        }
    }

    half8 o;
#pragma unroll
    for (int q = 0; q < 4; ++q) {
        o[q]     = (_Float16)a0[q];
        o[4 + q] = (_Float16)a1[q];
    }
    *(half8*)(agg + (size_t)n * 256 + l32 * 8) = o;
}

// ---------------- fused MLP: h2 = (relu(agg@W1+b1))@W2 + b2, + BN stats ---
// R26 = EXACT R12 mlp (891.9us total, best of session; mlp 100-102us
// stable across 3 containers). Closed experiment ledger:
//   occupancy 3->4 blocks/CU (R4): null        deep W-prefetch (R5): +5%
//   Us ping-pong 1-barrier (R9):  -10%         Us=128 low-LDS (R11): -12%
//   bn-fold w/ threadfence (R8):  -200% (L2 wbinv poison)
//   T5 setprio on MFMA (R13):     -7%  (m190-class: lockstep waves)
// No pipe >60%; this is the structure's floor. FINAL.
__global__ __launch_bounds__(256, 3) void k_fused_mlp(
    _Float16* __restrict__ H2, const _Float16* __restrict__ A,
    const short* __restrict__ W1p, const float* __restrict__ b1,
    const short* __restrict__ W2p, const float* __restrict__ b2,
    float* __restrict__ stats)
{
    __shared__ __align__(16) char smem[40960];
    _Float16* As = (_Float16*)smem;              // [64][256] granule-XOR, 32 KB
    _Float16* Us = (_Float16*)(smem + 32768);    // [64][64] granule-XOR, 8 KB
    _Float16* Cs = (_Float16*)smem;              // epilogue [64][264] (overlay)

    const int t = threadIdx.x;
    const int w = t >> 6, lane = t & 63;
    const int quad = lane >> 4, l16 = lane & 15;
    const int bm = blockIdx.x;
    const int gm0 = bm * 64;
    const int swz = l16 & 7;

    // stage A tile (64x256 f16 = 32 KB), granule g of row r at slot g^(r&7)
#pragma unroll
    for (int i = 0; i < 8; ++i) {
        int u = i * 256 + t;            // 2048 granules
        int row = u >> 5;
        int gcol = (u & 31) ^ (row & 7);
        int grow = gm0 + row; if (grow > NN - 1) grow = NN - 1;
        async_load16(A + (size_t)grow * 256 + gcol * 8, (char*)As + u * 16);
    }

    // per-wave weight base pointers (frag = base + elem-offset)
    const _Float16* w1w = (const _Float16*)W1p + ((size_t)(w * 16 + l16)) * 32 + quad * 8;
    const _Float16* w2w = (const _Float16*)W2p + ((size_t)(w * 64 + l16)) * 32 + quad * 8;

    // deep prefetch: chunk 0's full W1 (8 frags) + kk=0 W2 (4 frags)
    half8 w1buf[8];
#pragma unroll
    for (int i = 0; i < 8; ++i)
        w1buf[i] = *(const half8*)(w1w + ((size_t)i * 512) * 32);
    half8 w2k0[4];
#pragma unroll
    for (int nt = 0; nt < 4; ++nt)
        w2k0[nt] = *(const half8*)(w2w + ((size_t)nt * 16) * 32);

    f32x4 acc2[4][4];
#pragma unroll
    for (int i = 0; i < 4; ++i)
#pragma unroll
        for (int j = 0; j < 4; ++j) acc2[i][j] = (f32x4){0.f, 0.f, 0.f, 0.f};

    __syncthreads();   // staging barrier: must drain vmcnt (global_load_lds)

    for (int j = 0; j < 8; ++j) {
        // ---- GEMM1 chunk: U^T (64 uc x 64 ur) — pure LDS+MFMA, no VMEM --
        f32x4 acc1[4];
#pragma unroll
        for (int b = 0; b < 4; ++b) acc1[b] = (f32x4){0.f, 0.f, 0.f, 0.f};

#pragma unroll
        for (int kb = 0; kb < 8; ++kb) {
            int slotA = (kb * 4 + quad) ^ swz;
            half8 b1f[4];
#pragma unroll
            for (int urt = 0; urt < 4; ++urt)
                b1f[urt] = *(const half8*)(As + (urt * 16 + l16) * 256 + slotA * 8);
#pragma unroll
            for (int urt = 0; urt < 4; ++urt)
                acc1[urt] = __builtin_amdgcn_mfma_f32_16x16x32_f16(
                    w1buf[kb], b1f[urt], acc1[urt], 0, 0, 0);
        }

        // issue kk=1 W2 frags NOW -> latency hides under Us-write + barrier
        half8 a2n[4];
#pragma unroll
        for (int nt = 0; nt < 4; ++nt)
            a2n[nt] = *(const half8*)(w2w + ((size_t)(j * 2 + 1) * 256 + nt * 16) * 32);

        // write U chunk: relu(v+b1) -> f16, granule G of row ur at G^(ur&7)
        {
            int ucl = w * 16 + quad * 4;
            float4 bv = *(const float4*)(b1 + j * 64 + ucl);
            int G = ucl >> 3;
            int hs = quad & 1;
#pragma unroll
            for (int urt = 0; urt < 4; ++urt) {
                int ur = urt * 16 + l16;
                int S = G ^ (ur & 7);
                half4v o;
                o[0] = (_Float16)fmaxf(acc1[urt][0] + bv.x, 0.f);
                o[1] = (_Float16)fmaxf(acc1[urt][1] + bv.y, 0.f);
                o[2] = (_Float16)fmaxf(acc1[urt][2] + bv.z, 0.f);
                o[3] = (_Float16)fmaxf(acc1[urt][3] + bv.w, 0.f);
                *(half4v*)(Us + ur * 64 + S * 8 + hs * 4) = o;
            }
        }
        // LDS-only hazard: Us writes -> Us reads. Do NOT drain vmcnt here.
        asm volatile("s_waitcnt lgkmcnt(0)" ::: "memory");
        __builtin_amdgcn_s_barrier();
        __builtin_amdgcn_sched_barrier(0);

        // ---- GEMM2: refill next chunk's W1 (needed next GEMM1) ----
        if (j < 7) {
#pragma unroll
            for (int i = 0; i < 8; ++i)
                w1buf[i] = *(const half8*)(w1w + ((size_t)i * 512 + (j + 1) * 64) * 32);
        }

        // kk = 0 (weights in w2k0, prefetched one full chunk ago)
        {
            int slotU = quad ^ swz;
            half8 b2f[4];
#pragma unroll
            for (int mt = 0; mt < 4; ++mt)
                b2f[mt] = *(const half8*)(Us + (mt * 16 + l16) * 64 + slotU * 8);
#pragma unroll
            for (int nt = 0; nt < 4; ++nt)
#pragma unroll
                for (int mt = 0; mt < 4; ++mt)
                    acc2[nt][mt] = __builtin_amdgcn_mfma_f32_16x16x32_f16(
                        w2k0[nt], b2f[mt], acc2[nt][mt], 0, 0, 0);
        }
        // refill w2k0 for next chunk's kk=0
        if (j < 7) {
#pragma unroll
            for (int nt = 0; nt < 4; ++nt)
                w2k0[nt] = *(const half8*)(w2w + ((size_t)(j + 1) * 2 * 256 + nt * 16) * 32);
        }
        // kk = 1 (weights in a2n)
        {
            int slotU = (4 + quad) ^ swz;
            half8 b2f[4];
#pragma unroll
            for (int mt = 0; mt < 4; ++mt)
                b2f[mt] = *(const half8*)(Us + (mt * 16 + l16) * 64 + slotU * 8);
#pragma unroll
            for (int nt = 0; nt < 4; ++nt)
#pragma unroll
                for (int mt = 0; mt < 4; ++mt)
                    acc2[nt][mt] = __builtin_amdgcn_mfma_f32_16x16x32_f16(
                        a2n[nt], b2f[mt], acc2[nt][mt], 0, 0, 0);
        }
        // LDS-only hazard: Us reads -> next chunk's Us writes.
        asm volatile("s_waitcnt lgkmcnt(0)" ::: "memory");
        __builtin_amdgcn_s_barrier();
        __builtin_amdgcn_sched_barrier(0);
    }

    // ---- epilogue: bias + BN stats, coalesced store via LDS overlay ----
    int slot2 = bm & 63;
#pragma unroll
    for (int nt = 0; nt < 4; ++nt) {
        int nb = w * 64 + nt * 16 + quad * 4;
        float4 bv = *(const float4*)(b2 + nb);
        float s1[4] = {0.f, 0.f, 0.f, 0.f};
        float s2[4] = {0.f, 0.f, 0.f, 0.f};
#pragma unroll
        for (int mt = 0; mt < 4; ++mt) {
            int mr = mt * 16 + l16;
            int m = gm0 + mr;
            float v0 = acc2[nt][mt][0] + bv.x;
            float v1 = acc2[nt][mt][1] + bv.y;
            float v2 = acc2[nt][mt][2] + bv.z;
            float v3 = acc2[nt][mt][3] + bv.w;
            half4v o;
            o[0] = (_Float16)v0; o[1] = (_Float16)v1;
            o[2] = (_Float16)v2; o[3] = (_Float16)v3;
            *(half4v*)(Cs + mr * 264 + nb) = o;
            if (m < NN) {
                s1[0] += v0; s1[1] += v1; s1[2] += v2; s1[3] += v3;
                s2[0] += v0 * v0; s2[1] += v1 * v1;
                s2[2] += v2 * v2; s2[3] += v3 * v3;
            }
        }
#pragma unroll
        for (int r = 0; r < 4; ++r) {
            s1[r] += __shfl_xor(s1[r], 1, 64); s2[r] += __shfl_xor(s2[r], 1, 64);
            s1[r] += __shfl_xor(s1[r], 2, 64); s2[r] += __shfl_xor(s2[r], 2, 64);
            s1[r] += __shfl_xor(s1[r], 4, 64); s2[r] += __shfl_xor(s2[r], 4, 64);
            s1[r] += __shfl_xor(s1[r], 8, 64); s2[r] += __shfl_xor(s2[r], 8, 64);
            if (l16 == 0) {
                atomicAdd(&stats[slot2 * 512 + nb + r], s1[r]);
                atomicAdd(&stats[slot2 * 512 + 256 + nb + r], s2[r]);
            }
        }
    }
    __syncthreads();
#pragma unroll
    for (int i = 0; i < 8; ++i) {
        int u = i * 256 + t;
        int m = u >> 5, ch = u & 31;
        int grow = gm0 + m;
        if (grow < NN)
            *(int4*)(H2 + (size_t)grow * 256 + ch * 8) =
                *(const int4*)(Cs + m * 264 + ch * 8);
    }
}

// ---------------- BN finalize (+zero stats for next layer) ----------------
__global__ __launch_bounds__(256) void k_bn_finalize(
    float* __restrict__ scale, float* __restrict__ shift,
    float* __restrict__ stats,
    const float* __restrict__ bn_g, const float* __restrict__ bn_b)
{
    int t = threadIdx.x;
    float s1 = 0.f, s2 = 0.f;
    for (int j = 0; j < 64; ++j) {
        s1 += stats[j * 512 + t];
        s2 += stats[j * 512 + 256 + t];
        stats[j * 512 + t] = 0.f;
        stats[j * 512 + 256 + t] = 0.f;
    }
    float mu  = s1 / (float)NN;
    float var = s2 / (float)NN - mu * mu;
    float sc  = bn_g[t] * rsqrtf(var + 1e-5f);
    scale[t] = sc;
    shift[t] = bn_b[t] - mu * sc;
}

// ---------------- pool (R24: vectorized half8 loads, 8 rows in flight) ---
__global__ __launch_bounds__(256) void k_pool(
    float* __restrict__ mol, const _Float16* __restrict__ h,
    const int* __restrict__ goffs,
    const float* __restrict__ scale, const float* __restrict__ shift)
{
    __shared__ float red[8][256];
    int g = blockIdx.x;
    int t = threadIdx.x;
    int rg = t >> 5, c8 = t & 31;
    int s = goffs[g], e = goffs[g + 1];

    float acc[8] = {0.f,0.f,0.f,0.f,0.f,0.f,0.f,0.f};
    for (int n = s + rg; n < e; n += 8) {
        half8 v = *(const half8*)(h + (size_t)n * 256 + c8 * 8);
#pragma unroll
        for (int q = 0; q < 8; ++q) acc[q] += (float)v[q];
    }
#pragma unroll
    for (int q = 0; q < 8; ++q) red[rg][c8 * 8 + q] = acc[q];
    __syncthreads();

    float sum = 0.f;
#pragma unroll
    for (int r = 0; r < 8; ++r) sum += red[r][t];
    int c = e - s; if (c < 1) c = 1;
    mol[(size_t)g * 256 + t] = fmaf(sum / (float)c, scale[t], shift[t]);
}

// ---------------- head MLP, 4 graphs/block, 1000 blocks ----------------
__global__ __launch_bounds__(256) void k_head(
    float* __restrict__ out, const float* __restrict__ mol,
    const float* __restrict__ hW0, const float* __restrict__ hb0,
    const float* __restrict__ hW1, const float* __restrict__ hb1,
    const float* __restrict__ hW2, const float* __restrict__ hb2,
    const float* __restrict__ hW3, const float* __restrict__ hb3,
    const float* __restrict__ hWo, const float* __restrict__ hbo)
{
    __shared__ float za[GPB][256];
    __shared__ float zb[GPB][256];
    const int t = threadIdx.x;
    const int g0 = blockIdx.x * GPB;

#pragma unroll
    for (int g = 0; g < GPB; ++g)
        za[g][t] = mol[(size_t)(g0 + g) * 256 + t];
    __syncthreads();

    {
        float acc[GPB];
#pragma unroll
        for (int g = 0; g < GPB; ++g) acc[g] = 0.f;
        for (int k = 0; k < 256; ++k) {
            float w = hW0[k * 256 + t];
#pragma unroll
            for (int g = 0; g < GPB; ++g) acc[g] = fmaf(za[g][k], w, acc[g]);
        }
        float b = hb0[t];
#pragma unroll
        for (int g = 0; g < GPB; ++g) zb[g][t] = fmaxf(acc[g] + b, 0.f);
    }
    __syncthreads();

    if (t < 128) {
        float acc[GPB];
#pragma unroll
        for (int g = 0; g < GPB; ++g) acc[g] = 0.f;
        for (int k = 0; k < 256; ++k) {
            float w = hW1[k * 128 + t];
#pragma unroll
            for (int g = 0; g < GPB; ++g) acc[g] = fmaf(zb[g][k], w, acc[g]);
        }
        float b = hb1[t];
#pragma unroll
        for (int g = 0; g < GPB; ++g) za[g][t] = fmaxf(acc[g] + b, 0.f);
    }
    __syncthreads();

    if (t < 64) {
        float acc[GPB];
#pragma unroll
        for (int g = 0; g < GPB; ++g) acc[g] = 0.f;
        for (int k = 0; k < 128; ++k) {
            float w = hW2[k * 64 + t];
#pragma unroll
            for (int g = 0; g < GPB; ++g) acc[g] = fmaf(za[g][k], w, acc[g]);
        }
        float b = hb2[t];
#pragma unroll
        for (int g = 0; g < GPB; ++g) zb[g][t] = fmaxf(acc[g] + b, 0.f);
    }
    __syncthreads();

    if (t < 32) {
        float acc[GPB];
#pragma unroll
        for (int g = 0; g < GPB; ++g) acc[g] = 0.f;
        for (int k = 0; k < 64; ++k) {
            float w = hW3[k * 32 + t];
#pragma unroll
            for (int g = 0; g < GPB; ++g) acc[g] = fmaf(zb[g][k], w, acc[g]);
        }
        float b = hb3[t];
#pragma unroll
        for (int g = 0; g < GPB; ++g) za[g][t] = fmaxf(acc[g] + b, 0.f);
    }
    __syncthreads();

    if (t < GPB) {
        float s = hbo[0];
        for (int k = 0; k < 32; ++k) s = fmaf(za[t][k], hWo[k], s);
        out[g0 + t] = s;
    }
}

extern "C" void kernel_launch(void* const* d_in, const int* in_sizes, int n_in,
                              void* d_out, int out_size, void* d_ws, size_t ws_size,
                              hipStream_t stream)
{
    const float* x    = (const float*)d_in[0];
    const int*   ei   = (const int*)d_in[1];
    const int*   ea   = (const int*)d_in[2];
    const int*   batch= (const int*)d_in[3];
    const float* embW = (const float*)d_in[4];
    const float* embB = (const float*)d_in[5];
    const float* ee1  = (const float*)d_in[6];
    const float* ee2  = (const float*)d_in[7];
    const float* W1   = (const float*)d_in[8];
    const float* b1   = (const float*)d_in[9];
    const float* W2   = (const float*)d_in[10];
    const float* b2   = (const float*)d_in[11];
    const float* bng  = (const float*)d_in[12];
    const float* bnb  = (const float*)d_in[13];
    const float* hW0  = (const float*)d_in[14];
    const float* hb0  = (const float*)d_in[15];
    const float* hW1  = (const float*)d_in[16];
    const float* hb1  = (const float*)d_in[17];
    const float* hW2  = (const float*)d_in[18];
    const float* hb2  = (const float*)d_in[19];
    const float* hW3  = (const float*)d_in[20];
    const float* hb3  = (const float*)d_in[21];
    const float* hWo  = (const float*)d_in[22];
    const float* hbo  = (const float*)d_in[23];
    float* out = (float*)d_out;

    char* ws = (char*)d_ws;
    size_t off = 0;
    _Float16* h2buf = (_Float16*)(ws + off); off += (size_t)NN * 256 * 2;
    _Float16* aggbuf= (_Float16*)(ws + off); off += (size_t)NN * 256 * 2;
    short* W1p      = (short*)(ws + off);    off += (size_t)5 * 131072 * 2;
    short* W2p      = (short*)(ws + off);    off += (size_t)5 * 131072 * 2;
    _Float16* Wep   = (_Float16*)(ws + off); off += (size_t)2 * 8192 * 2;
    float* tbl      = (float*)(ws + off);    off += (size_t)5 * 10 * 256 * 4;
    float* stats    = (float*)(ws + off);    off += (size_t)64 * 512 * 4;
    float* scale    = (float*)(ws + off);    off += 256 * 4;
    float* shift    = (float*)(ws + off);    off += 256 * 4;
    float* mol      = (float*)(ws + off);    off += (size_t)GG * 256 * 4;
    int* deg        = (int*)(ws + off);      off += (size_t)NN * 4;
    int* offs       = (int*)(ws + off);      off += (size_t)(NN + 1) * 4;
    int* cursor     = (int*)(ws + off);      off += (size_t)NN * 4;
    int* csr        = (int*)(ws + off);      off += (size_t)EE * 4;
    int* goffs      = (int*)(ws + off);      off += (size_t)(GG + 1) * 4;
    int* partial    = (int*)(ws + off);      off += 128 * 4;
    int* bases      = (int*)(ws + off);      off += 128 * 4;

    // ---- fused prologue (goffs/combo/packs/pack_emb/deg=0/stats=0) ----
    k_prologue<<<1568, 256, 0, stream>>>(goffs, batch, tbl, ee1, ee2,
                                         W1p, W1, W2p, W2, Wep, embW,
                                         deg, stats);
    k_count<<<(EE + 255) / 256, 256, 0, stream>>>(deg, ei);
    k_scan_partial<<<SC_NB, 256, 0, stream>>>(partial, deg);
    k_scan_base<<<1, 128, 0, stream>>>(bases, offs, partial);
    k_scan_final<<<SC_NB, 256, 0, stream>>>(offs, cursor, deg, bases);
    k_fill<<<(EE + 255) / 256, 256, 0, stream>>>(csr, cursor, ei, ea);

    k_embed_mfma<<<782, 256, 0, stream>>>(h2buf, x, Wep, embB);

    const int FB = (NN + 63) / 64;   // 1563
    for (int l = 0; l < LL; ++l) {
        if (l == 0)
            k_aggregate<0><<<NN / 8, 256, 0, stream>>>(aggbuf, h2buf, offs, csr,
                                                       tbl, scale, shift);
        else
            k_aggregate<1><<<NN / 8, 256, 0, stream>>>(aggbuf, h2buf, offs, csr,
                                                       tbl + (size_t)l * 10 * 256, scale, shift);
        k_fused_mlp<<<FB, 256, 0, stream>>>(h2buf, aggbuf,
                                            W1p + (size_t)l * 131072, b1 + l * 512,
                                            W2p + (size_t)l * 131072, b2 + l * 256, stats);
        k_bn_finalize<<<1, 256, 0, stream>>>(scale, shift, stats, bng + l * 256, bnb + l * 256);
    }

    k_pool<<<GG, 256, 0, stream>>>(mol, h2buf, goffs, scale, shift);
    k_head<<<GG / GPB, 256, 0, stream>>>(out, mol,
                                         hW0, hb0, hW1, hb1, hW2, hb2, hW3, hb3, hWo, hbo);
}